// Round 1
// baseline (135.290 us; speedup 1.0000x reference)
//
#include <hip/hip_runtime.h>
#include <hip/hip_bf16.h>
#include <math.h>

#define N_NODES 512
#define S_STEPS 64
#define M_EV    32768
#define DELTA_F 1.5625f
#define EPS_F   1e-12f
#define TILE    16
#define NT      (N_NODES / TILE)        // 32
#define NBLK    (NT * (NT + 1) / 2)     // 528

// ws layout (floats at base):
//   [0..63]    c0 (count per bucket)
//   [64..127]  c1 (sum dd)
//   [128..191] c2 (sum dd^2)
//   [192..255] ts
//   [256..319] occ (0/1)
//   [320..383] T = tf - ts
// byte offset 1536: double partials[NBLK*2]

__global__ void bucket_stats(const float* __restrict__ data, float* __restrict__ ws_f) {
    int s = blockIdx.x;          // bucket
    int lane = threadIdx.x;      // 0..63
    int   cnt  = 0;
    float sdd  = 0.f, sdd2 = 0.f;
    int   fpos = 0x7fffffff;
    for (int m = lane; m < M_EV; m += 64) {
        float t = data[3 * m + 2];
        float stepf = floorf(t / DELTA_F);
        float cl = fminf(fmaxf(stepf, 0.f), 63.f);
        int idx = (int)cl;
        if (idx == s) {
            float dd = t - stepf * DELTA_F;
            cnt++; sdd += dd; sdd2 += dd * dd;
            fpos = min(fpos, m);
        }
    }
    // deterministic wave-64 tree reduce
    for (int off = 32; off; off >>= 1) {
        cnt  += __shfl_down(cnt,  off);
        sdd  += __shfl_down(sdd,  off);
        sdd2 += __shfl_down(sdd2, off);
        fpos  = min(fpos, __shfl_down(fpos, off));
    }
    if (lane == 0) {
        ws_f[s]        = (float)cnt;
        ws_f[64 + s]   = sdd;
        ws_f[128 + s]  = sdd2;
        int fp = min(fpos, M_EV - 1);
        ws_f[192 + s]  = data[3 * fp + 2];
        ws_f[256 + s]  = (fpos < M_EV) ? 1.f : 0.f;
    }
}

__global__ void compute_T(const float* __restrict__ data, float* __restrict__ ws_f) {
    // single thread: reverse scan for tf, write T = tf - ts
    float carry = data[3 * (M_EV - 1) + 2];   // times[M-1]
    for (int s = S_STEPS - 1; s >= 0; --s) {
        float ts  = ws_f[192 + s];
        float occ = ws_f[256 + s];
        ws_f[320 + s] = carry - ts;           // tf[s] - ts[s]
        if (occ > 0.5f) carry = ts;
    }
}

__global__ __launch_bounds__(256) void pair_kernel(
        const float* __restrict__ z0, const float* __restrict__ v0,
        const float* __restrict__ beta, const float* __restrict__ ws_f,
        double* __restrict__ partials) {
    __shared__ float4 Pi[S_STEPS][TILE];
    __shared__ float4 Pj[S_STEPS][TILE];
    __shared__ float sc0[64], sc1[64], sc2[64], sT[64], socc[64];
    __shared__ float redD[256], redI[256];

    // map linear block -> upper-tri tile (it <= jt)
    int l = blockIdx.x;
    int it = 0, rem = l;
    while (rem >= NT - it) { rem -= NT - it; ++it; }
    int jt = it + rem;

    int tid = threadIdx.x;

    // stage per-step scalars
    if (tid >= 64 && tid < 128) {
        int s = tid - 64;
        sc0[s]  = ws_f[s];
        sc1[s]  = ws_f[64 + s];
        sc2[s]  = ws_f[128 + s];
        socc[s] = ws_f[256 + s];
        sT[s]   = ws_f[320 + s];
    }
    // stage position/velocity slabs: threads 0..15 -> i-slab, 16..31 -> j-slab
    if (tid < 32) {
        int local = tid & 15;
        bool isI = tid < 16;
        int n = (isI ? it : jt) * TILE + local;
        float zx = z0[2 * n], zy = z0[2 * n + 1];
        const float* vxp = v0 + n * 128;       // v0[n][0][*]
        const float* vyp = vxp + 64;           // v0[n][1][*]
        for (int s = 0; s < S_STEPS; ++s) {
            float vx = vxp[s], vy = vyp[s];
            float4 val = make_float4(zx, zy, vx, vy);
            if (isI) Pi[s][local] = val; else Pj[s][local] = val;
            zx += vx * DELTA_F; zy += vy * DELTA_F;
        }
    }
    __syncthreads();

    int li = tid >> 4, lj = tid & 15;
    int i = it * TILE + li, j = jt * TILE + lj;
    float accD = 0.f, accI = 0.f;
    float b = beta[0];

    if (i < j) {
        for (int s = 0; s < S_STEPS; ++s) {
            float4 a = Pi[s][li];
            float4 c = Pj[s][lj];
            float dx  = a.x - c.x,  dy  = a.y - c.y;
            float dvx = a.z - c.z,  dvy = a.w - c.w;
            float q  = dx * dx + dy * dy;
            float p  = dx * dvx + dy * dvy;
            float vv = dvx * dvx + dvy * dvy;
            accD += sc0[s] * q + 2.f * sc1[s] * p + sc2[s] * vv;
            float rr    = vv + EPS_F;
            float inv_r = rsqrtf(rr);
            float r     = rr * inv_r;           // sqrt(rr)
            float por   = p * inv_r;
            float ex    = expf(b - q + por * por);
            float integ = ex * (0.8862269254527580f * inv_r)
                          * (erff(r * sT[s] + por) - erff(por));
            accI += socc[s] * integ;
        }
    }

    redD[tid] = accD; redI[tid] = accI;
    __syncthreads();
    for (int off = 128; off; off >>= 1) {
        if (tid < off) { redD[tid] += redD[tid + off]; redI[tid] += redI[tid + off]; }
        __syncthreads();
    }
    if (tid == 0) {
        partials[2 * l]     = (double)redD[0];
        partials[2 * l + 1] = (double)redI[0];
    }
}

__global__ void final_reduce(const float* __restrict__ beta,
                             const double* __restrict__ partials,
                             float* __restrict__ out) {
    __shared__ double sD[256], sI[256];
    int tid = threadIdx.x;
    double dD = 0.0, dI = 0.0;
    for (int l = tid; l < NBLK; l += 256) {
        dD += partials[2 * l];
        dI += partials[2 * l + 1];
    }
    sD[tid] = dD; sI[tid] = dI;
    __syncthreads();
    for (int off = 128; off; off >>= 1) {
        if (tid < off) { sD[tid] += sD[tid + off]; sI[tid] += sI[tid + off]; }
        __syncthreads();
    }
    if (tid == 0) {
        double npairs = (double)N_NODES * (double)(N_NODES - 1) * 0.5;
        double ev = (double)beta[0] * (double)M_EV * npairs - sD[0];
        out[0] = (float)(ev - sI[0]);
    }
}

extern "C" void kernel_launch(void* const* d_in, const int* in_sizes, int n_in,
                              void* d_out, int out_size, void* d_ws, size_t ws_size,
                              hipStream_t stream) {
    const float* data = (const float*)d_in[0];
    // d_in[1] = t0, d_in[2] = tn (unused by reference math)
    const float* z0   = (const float*)d_in[3];
    const float* v0   = (const float*)d_in[4];
    const float* beta = (const float*)d_in[5];

    float*  ws_f     = (float*)d_ws;
    double* partials = (double*)((char*)d_ws + 1536);
    float*  out      = (float*)d_out;

    bucket_stats<<<64, 64, 0, stream>>>(data, ws_f);
    compute_T<<<1, 1, 0, stream>>>(data, ws_f);
    pair_kernel<<<NBLK, 256, 0, stream>>>(z0, v0, beta, ws_f, partials);
    final_reduce<<<1, 256, 0, stream>>>(beta, partials, out);
}

// Round 2
// 53.492 us; speedup vs baseline: 2.5292x; 2.5292x over previous
//
#include <hip/hip_runtime.h>
#include <hip/hip_bf16.h>
#include <math.h>

#define N_NODES 512
#define S_STEPS 64
#define M_EV    32768
#define DELTA_F 1.5625f
#define EPS_F   1e-12f
#define TILE    16
#define NT      (N_NODES / TILE)        // 32
#define NBLK    (NT * (NT + 1) / 2)     // 528

// ws layout (floats at base):
//   [0..63]    c0 (count per bucket)
//   [64..127]  c1 (sum dd)
//   [128..191] c2 (sum dd^2)
//   [192..255] ts
//   [256..319] occ (0/1)
//   [320..383] T = tf - ts
// byte offset 1536: double partials[NBLK*2]

__device__ __forceinline__ int bucket_key(float t) {
    float stepf = floorf(t / DELTA_F);
    float cl = fminf(fmaxf(stepf, 0.f), 63.f);
    return (int)cl;
}

// lower_bound: first m in [0,M) with bucket_key(times[m]) >= target
__device__ __forceinline__ int lower_bound_key(const float* __restrict__ data, int target) {
    int lo = 0, len = M_EV;
    while (len > 0) {
        int half = len >> 1;
        int mid = lo + half;
        if (bucket_key(data[3 * mid + 2]) < target) { lo = mid + 1; len -= half + 1; }
        else { len = half; }
    }
    return lo;
}

__global__ __launch_bounds__(256) void bucket_stats(const float* __restrict__ data,
                                                    float* __restrict__ ws_f) {
    int s   = blockIdx.x;       // bucket
    int tid = threadIdx.x;
    __shared__ int sLo, sHi;
    __shared__ int   wcnt[4];
    __shared__ float wsdd[4], wsdd2[4];

    // two binary searches in different waves -> run concurrently
    if (tid == 0)  sLo = lower_bound_key(data, s);
    if (tid == 64) sHi = lower_bound_key(data, s + 1);
    __syncthreads();
    int lo = sLo, hi = sHi;

    int   cnt = 0;
    float sdd = 0.f, sdd2 = 0.f;
    for (int m = lo + tid; m < hi; m += 256) {
        float t = data[3 * m + 2];
        float stepf = floorf(t / DELTA_F);   // unclipped, matches reference dd
        float dd = t - stepf * DELTA_F;
        cnt++; sdd += dd; sdd2 += dd * dd;
    }
    // wave-64 tree reduce (deterministic)
    for (int off = 32; off; off >>= 1) {
        cnt  += __shfl_down(cnt,  off);
        sdd  += __shfl_down(sdd,  off);
        sdd2 += __shfl_down(sdd2, off);
    }
    int wave = tid >> 6;
    if ((tid & 63) == 0) { wcnt[wave] = cnt; wsdd[wave] = sdd; wsdd2[wave] = sdd2; }
    __syncthreads();
    if (tid == 0) {
        int   c  = wcnt[0] + wcnt[1] + wcnt[2] + wcnt[3];
        float s1 = wsdd[0] + wsdd[1] + wsdd[2] + wsdd[3];
        float s2 = wsdd2[0] + wsdd2[1] + wsdd2[2] + wsdd2[3];
        ws_f[s]       = (float)c;
        ws_f[64 + s]  = s1;
        ws_f[128 + s] = s2;
        int fp = min(max(lo, 0), M_EV - 1);
        ws_f[192 + s] = data[3 * fp + 2];          // ts (finite even if empty)
        ws_f[256 + s] = (c > 0) ? 1.f : 0.f;       // occ
    }
}

__global__ void compute_T(const float* __restrict__ data, float* __restrict__ ws_f) {
    // single thread: reverse scan for tf, write T = tf - ts
    float carry = data[3 * (M_EV - 1) + 2];   // times[M-1]
    for (int s = S_STEPS - 1; s >= 0; --s) {
        float ts  = ws_f[192 + s];
        float occ = ws_f[256 + s];
        ws_f[320 + s] = carry - ts;           // tf[s] - ts[s]
        if (occ > 0.5f) carry = ts;
    }
}

__global__ __launch_bounds__(256) void pair_kernel(
        const float* __restrict__ z0, const float* __restrict__ v0,
        const float* __restrict__ beta, const float* __restrict__ ws_f,
        double* __restrict__ partials) {
    __shared__ float4 Pi[S_STEPS][TILE];
    __shared__ float4 Pj[S_STEPS][TILE];
    __shared__ float sc0[64], sc1[64], sc2[64], sT[64], socc[64];
    __shared__ float redD[256], redI[256];

    // map linear block -> upper-tri tile (it <= jt)
    int l = blockIdx.x;
    int it = 0, rem = l;
    while (rem >= NT - it) { rem -= NT - it; ++it; }
    int jt = it + rem;

    int tid = threadIdx.x;

    // stage per-step scalars
    if (tid >= 64 && tid < 128) {
        int s = tid - 64;
        sc0[s]  = ws_f[s];
        sc1[s]  = ws_f[64 + s];
        sc2[s]  = ws_f[128 + s];
        socc[s] = ws_f[256 + s];
        sT[s]   = ws_f[320 + s];
    }
    // stage position/velocity slabs: threads 0..15 -> i-slab, 16..31 -> j-slab
    if (tid < 32) {
        int local = tid & 15;
        bool isI = tid < 16;
        int n = (isI ? it : jt) * TILE + local;
        float zx = z0[2 * n], zy = z0[2 * n + 1];
        const float* vxp = v0 + n * 128;       // v0[n][0][*]
        const float* vyp = vxp + 64;           // v0[n][1][*]
        for (int s = 0; s < S_STEPS; ++s) {
            float vx = vxp[s], vy = vyp[s];
            float4 val = make_float4(zx, zy, vx, vy);
            if (isI) Pi[s][local] = val; else Pj[s][local] = val;
            zx += vx * DELTA_F; zy += vy * DELTA_F;
        }
    }
    __syncthreads();

    int li = tid >> 4, lj = tid & 15;
    int i = it * TILE + li, j = jt * TILE + lj;
    float accD = 0.f, accI = 0.f;
    float b = beta[0];

    if (i < j) {
        for (int s = 0; s < S_STEPS; ++s) {
            float4 a = Pi[s][li];
            float4 c = Pj[s][lj];
            float dx  = a.x - c.x,  dy  = a.y - c.y;
            float dvx = a.z - c.z,  dvy = a.w - c.w;
            float q  = dx * dx + dy * dy;
            float p  = dx * dvx + dy * dvy;
            float vv = dvx * dvx + dvy * dvy;
            accD += sc0[s] * q + 2.f * sc1[s] * p + sc2[s] * vv;
            float rr    = vv + EPS_F;
            float inv_r = rsqrtf(rr);
            float r     = rr * inv_r;           // sqrt(rr)
            float por   = p * inv_r;
            float ex    = expf(b - q + por * por);
            float integ = ex * (0.8862269254527580f * inv_r)
                          * (erff(r * sT[s] + por) - erff(por));
            accI += socc[s] * integ;
        }
    }

    redD[tid] = accD; redI[tid] = accI;
    __syncthreads();
    for (int off = 128; off; off >>= 1) {
        if (tid < off) { redD[tid] += redD[tid + off]; redI[tid] += redI[tid + off]; }
        __syncthreads();
    }
    if (tid == 0) {
        partials[2 * l]     = (double)redD[0];
        partials[2 * l + 1] = (double)redI[0];
    }
}

__global__ void final_reduce(const float* __restrict__ beta,
                             const double* __restrict__ partials,
                             float* __restrict__ out) {
    __shared__ double sD[256], sI[256];
    int tid = threadIdx.x;
    double dD = 0.0, dI = 0.0;
    for (int l = tid; l < NBLK; l += 256) {
        dD += partials[2 * l];
        dI += partials[2 * l + 1];
    }
    sD[tid] = dD; sI[tid] = dI;
    __syncthreads();
    for (int off = 128; off; off >>= 1) {
        if (tid < off) { sD[tid] += sD[tid + off]; sI[tid] += sI[tid + off]; }
        __syncthreads();
    }
    if (tid == 0) {
        double npairs = (double)N_NODES * (double)(N_NODES - 1) * 0.5;
        double ev = (double)beta[0] * (double)M_EV * npairs - sD[0];
        out[0] = (float)(ev - sI[0]);
    }
}

extern "C" void kernel_launch(void* const* d_in, const int* in_sizes, int n_in,
                              void* d_out, int out_size, void* d_ws, size_t ws_size,
                              hipStream_t stream) {
    const float* data = (const float*)d_in[0];
    // d_in[1] = t0, d_in[2] = tn (unused by reference math)
    const float* z0   = (const float*)d_in[3];
    const float* v0   = (const float*)d_in[4];
    const float* beta = (const float*)d_in[5];

    float*  ws_f     = (float*)d_ws;
    double* partials = (double*)((char*)d_ws + 1536);
    float*  out      = (float*)d_out;

    bucket_stats<<<64, 256, 0, stream>>>(data, ws_f);
    compute_T<<<1, 1, 0, stream>>>(data, ws_f);
    pair_kernel<<<NBLK, 256, 0, stream>>>(z0, v0, beta, ws_f, partials);
    final_reduce<<<1, 256, 0, stream>>>(beta, partials, out);
}